// Round 1
// baseline (1383.382 us; speedup 1.0000x reference)
//
#include <hip/hip_runtime.h>
#include <hip/hip_bf16.h>

#define NN 50000
#define EE 500000
#define GG 64
#define IN_F 128
#define H_F 64
#define HEADS 4
#define OUT_F 326000
#define NEG 0.2f

// ---------------- embedding GEMM: h0 = x @ W_emb + b_emb ----------------
// block 256 = 4 waves; wave j handles nodes base+j+4i; lane = output channel c.
__global__ void k_emb(const float* __restrict__ x, const float* __restrict__ Wemb,
                      const float* __restrict__ bemb, float* __restrict__ h0) {
    int t = threadIdx.x;
    int c = t & 63, sub = t >> 6;
    float wreg[IN_F];
#pragma unroll
    for (int k = 0; k < IN_F; ++k) wreg[k] = Wemb[k * H_F + c];
    float bv = bemb[c];
    int base = blockIdx.x * 32;
    for (int i = 0; i < 8; ++i) {
        int n = base + sub + 4 * i;
        if (n >= NN) continue;
        const float* xr = x + (size_t)n * IN_F;
        float acc = 0.f;
#pragma unroll
        for (int k = 0; k < IN_F; ++k) acc += xr[k] * wreg[k];
        h0[(size_t)n * H_F + c] = acc + bv;
    }
}

// ---------------- per-layer GEMM: xbuf = h @ W, plus ls/ld via wave reduce ----
// block 256 threads = all 256 output cols of ONE node at a time; wave w = head w.
__global__ void k_gemm_layer(const float* __restrict__ h, const float* __restrict__ W,
                             const float* __restrict__ a_src, const float* __restrict__ a_dst,
                             float* __restrict__ xbuf, float* __restrict__ ls,
                             float* __restrict__ ld) {
    int t = threadIdx.x;
    int lane = t & 63, wv = t >> 6;
    float wreg[H_F];
#pragma unroll
    for (int k = 0; k < H_F; ++k) wreg[k] = W[k * (HEADS * H_F) + t];
    float asv = a_src[t], adv = a_dst[t];
    int base = blockIdx.x * 32;
    for (int i = 0; i < 32; ++i) {
        int n = base + i;
        if (n >= NN) return;
        const float* hr = h + (size_t)n * H_F;
        float acc = 0.f;
#pragma unroll
        for (int k = 0; k < H_F; ++k) acc += hr[k] * wreg[k];
        xbuf[(size_t)n * (HEADS * H_F) + t] = acc;
        float vs = acc * asv, vd = acc * adv;
#pragma unroll
        for (int off = 32; off; off >>= 1) {
            vs += __shfl_xor(vs, off, 64);
            vd += __shfl_xor(vd, off, 64);
        }
        if (lane == 0) {
            ls[n * HEADS + wv] = vs;
            ld[n * HEADS + wv] = vd;
        }
    }
}

__device__ __forceinline__ float lrelu_exp(float e) {
    e = (e > 0.f) ? e : NEG * e;
    return __expf(e);
}

// ---------------- edge pass 1: denom[dst,h] += exp(lrelu(ls[src]+ld[dst])) ----
__global__ void k_edge_denom(const int* __restrict__ src, const int* __restrict__ dst,
                             const float4* __restrict__ ls4, const float4* __restrict__ ld4,
                             float* __restrict__ den) {
    int i = blockIdx.x * blockDim.x + threadIdx.x;
    if (i >= EE + NN) return;
    int s, d;
    if (i < EE) { s = src[i]; d = dst[i]; } else { s = d = i - EE; }
    float4 a = ls4[s];
    float4 b = ld4[d];
    atomicAdd(&den[d * HEADS + 0], lrelu_exp(a.x + b.x));
    atomicAdd(&den[d * HEADS + 1], lrelu_exp(a.y + b.y));
    atomicAdd(&den[d * HEADS + 2], lrelu_exp(a.z + b.z));
    atomicAdd(&den[d * HEADS + 3], lrelu_exp(a.w + b.w));
}

// ---------------- edge pass 2: acc[dst,c] += (1/4) sum_h alpha[e,h]*x[src,h,c] --
// one wave per edge (lane = channel c), grid-stride over edges.
__global__ void k_edge_aggr(const int* __restrict__ src, const int* __restrict__ dst,
                            const float4* __restrict__ ls4, const float4* __restrict__ ld4,
                            const float4* __restrict__ den4, const float* __restrict__ xbuf,
                            float* __restrict__ accb, int totalWaves) {
    int lane = threadIdx.x & 63;
    int wave = (blockIdx.x * blockDim.x + threadIdx.x) >> 6;
    for (int e = wave; e < EE + NN; e += totalWaves) {
        int s, d;
        if (e < EE) { s = src[e]; d = dst[e]; } else { s = d = e - EE; }
        s = __builtin_amdgcn_readfirstlane(s);
        d = __builtin_amdgcn_readfirstlane(d);
        float4 a = ls4[s];
        float4 b = ld4[d];
        float4 dn = den4[d];
        float w0 = lrelu_exp(a.x + b.x) / (dn.x + 1e-16f) * 0.25f;
        float w1 = lrelu_exp(a.y + b.y) / (dn.y + 1e-16f) * 0.25f;
        float w2 = lrelu_exp(a.z + b.z) / (dn.z + 1e-16f) * 0.25f;
        float w3 = lrelu_exp(a.w + b.w) / (dn.w + 1e-16f) * 0.25f;
        const float* xp = xbuf + (size_t)s * (HEADS * H_F);
        float acc = w0 * xp[lane] + w1 * xp[64 + lane] + w2 * xp[128 + lane] + w3 * xp[192 + lane];
        atomicAdd(&accb[(size_t)d * H_F + lane], acc);
    }
}

// ---------------- finalize: h = relu(acc + b), in place, float4 --------------
__global__ void k_finalize(float* __restrict__ h, const float* __restrict__ bias) {
    int i = blockIdx.x * blockDim.x + threadIdx.x;  // float4 index
    if (i >= NN * (H_F / 4)) return;
    float4 v = ((float4*)h)[i];
    float4 b = ((const float4*)bias)[i & 15];
    v.x = fmaxf(v.x + b.x, 0.f);
    v.y = fmaxf(v.y + b.y, 0.f);
    v.z = fmaxf(v.z + b.z, 0.f);
    v.w = fmaxf(v.w + b.w, 0.f);
    ((float4*)h)[i] = v;
}

// ---------------- graph starts via binary search on sorted batch -------------
__global__ void k_starts(const int* __restrict__ batch, int* __restrict__ starts) {
    int g = threadIdx.x;
    if (g > GG) return;
    int lo = 0, hi = NN;
    while (lo < hi) {
        int mid = (lo + hi) >> 1;
        if (batch[mid] < g) lo = mid + 1; else hi = mid;
    }
    starts[g] = lo;
}

// ---------------- pooling: pooledT[c][g] = mean over nodes of graph g --------
__global__ void k_pool(const float* __restrict__ h, const int* __restrict__ starts,
                       float* __restrict__ pooledT) {
    int g = blockIdx.x;
    int s = starts[g], e = starts[g + 1];
    int t = threadIdx.x;
    int c = t & 63, j = t >> 6;
    float sum = 0.f;
    for (int n = s + j; n < e; n += 4) sum += h[(size_t)n * H_F + c];
    __shared__ float lds[256];
    lds[t] = sum;
    __syncthreads();
    if (j == 0) {
        float tot = lds[c] + lds[64 + c] + lds[128 + c] + lds[192 + c];
        int cnt = e - s;
        float inv = 1.0f / (float)(cnt > 0 ? cnt : 1);
        pooledT[c * GG + g] = tot * inv;
    }
}

// ---------------- final FC: out[g,o] = sum_c pooledT[c][g]*Wfc[c,o] + bfc[o] --
__global__ void k_fc(const float* __restrict__ pooledT, const float* __restrict__ Wfc,
                     const float* __restrict__ bfc, float* __restrict__ out) {
    int o = blockIdx.x * blockDim.x + threadIdx.x;
    if (o >= OUT_F) return;
    float acc[GG];
#pragma unroll
    for (int g = 0; g < GG; ++g) acc[g] = 0.f;
    for (int c = 0; c < H_F; ++c) {
        float wvv = Wfc[(size_t)c * OUT_F + o];
        const float* pr = pooledT + c * GG;
#pragma unroll
        for (int g = 0; g < GG; ++g) acc[g] += pr[g] * wvv;
    }
    float bv = bfc[o];
    for (int g = 0; g < GG; ++g) out[(size_t)g * OUT_F + o] = acc[g] + bv;
}

extern "C" void kernel_launch(void* const* d_in, const int* in_sizes, int n_in,
                              void* d_out, int out_size, void* d_ws, size_t ws_size,
                              hipStream_t stream) {
    const float* x      = (const float*)d_in[0];
    const int*   eidx   = (const int*)d_in[1];
    const int*   batch  = (const int*)d_in[3];
    const float* W_emb  = (const float*)d_in[4];
    const float* b_emb  = (const float*)d_in[5];
    const float* W_fc   = (const float*)d_in[6];
    const float* b_fc   = (const float*)d_in[7];
    const float* Wl[3]   = {(const float*)d_in[8],  (const float*)d_in[12], (const float*)d_in[16]};
    const float* asl[3]  = {(const float*)d_in[9],  (const float*)d_in[13], (const float*)d_in[17]};
    const float* adl[3]  = {(const float*)d_in[10], (const float*)d_in[14], (const float*)d_in[18]};
    const float* bl[3]   = {(const float*)d_in[11], (const float*)d_in[15], (const float*)d_in[19]};

    const int* src = eidx;
    const int* dst = eidx + EE;

    // workspace carving (all float-aligned, total ~79 MB)
    float* xbuf    = (float*)d_ws;                     // N*256
    float* hA      = xbuf + (size_t)NN * 256;          // N*64
    float* hB      = hA + (size_t)NN * 64;             // N*64
    float* ls      = hB + (size_t)NN * 64;             // N*4
    float* ldb     = ls + (size_t)NN * 4;              // N*4
    float* den     = ldb + (size_t)NN * 4;             // N*4
    float* pooledT = den + (size_t)NN * 4;             // 64*64
    int*   starts  = (int*)(pooledT + GG * GG);        // 65

    k_emb<<<(NN + 31) / 32, 256, 0, stream>>>(x, W_emb, b_emb, hA);

    float* hcur = hA;
    float* hnext = hB;
    for (int l = 0; l < 3; ++l) {
        k_gemm_layer<<<(NN + 31) / 32, 256, 0, stream>>>(hcur, Wl[l], asl[l], adl[l],
                                                         xbuf, ls, ldb);
        hipMemsetAsync(den, 0, (size_t)NN * 4 * sizeof(float), stream);
        hipMemsetAsync(hnext, 0, (size_t)NN * 64 * sizeof(float), stream);
        k_edge_denom<<<(EE + NN + 255) / 256, 256, 0, stream>>>(
            src, dst, (const float4*)ls, (const float4*)ldb, den);
        const int aggrBlocks = 2048;  // 4 waves each -> 8192 waves, grid-stride
        k_edge_aggr<<<aggrBlocks, 256, 0, stream>>>(
            src, dst, (const float4*)ls, (const float4*)ldb, (const float4*)den,
            xbuf, hnext, aggrBlocks * 4);
        k_finalize<<<(NN * 16 + 255) / 256, 256, 0, stream>>>(hnext, bl[l]);
        float* tmp = hcur; hcur = hnext; hnext = tmp;
    }

    k_starts<<<1, 128, 0, stream>>>(batch, starts);
    k_pool<<<GG, 256, 0, stream>>>(hcur, starts, pooledT);
    k_fc<<<(OUT_F + 255) / 256, 256, 0, stream>>>(pooledT, W_fc, b_fc, (float*)d_out);
}